// Round 1
// baseline (1069.925 us; speedup 1.0000x reference)
//
#include <hip/hip_runtime.h>

#define NROWS 8192
#define TDIM 768
#define IDIM 1024
#define DDIM 1024
#define NEXP 8
#define GHID 512

typedef __attribute__((ext_vector_type(8))) short short8;
typedef __attribute__((ext_vector_type(4))) float f4;
typedef __attribute__((ext_vector_type(4))) unsigned short us4;

__device__ __forceinline__ unsigned short f2bf(float f) {
  union { float f; unsigned u; } v; v.f = f;
  unsigned r = v.u + 0x7FFF + ((v.u >> 16) & 1);
  return (unsigned short)(r >> 16);
}
__device__ __forceinline__ float bf2f(unsigned short u) {
  union { unsigned u; float f; } v; v.u = ((unsigned)u) << 16;
  return v.f;
}

__device__ __forceinline__ void gload16(const void* g, void* l) {
  __builtin_amdgcn_global_load_lds(
      (const __attribute__((address_space(1))) void*)g,
      (__attribute__((address_space(3))) void*)l, 16, 0, 0);
}

// ---------------- fp32 -> bf16 elementwise cast (vectorized) ----------------
__global__ __launch_bounds__(256) void cast_bf16_kernel(
    const float* __restrict__ src, unsigned short* __restrict__ dst, int n4) {
  int i = blockIdx.x * 256 + threadIdx.x;
  if (i < n4) {
    f4 v = ((const f4*)src)[i];
    us4 o;
    o[0] = f2bf(v[0]); o[1] = f2bf(v[1]); o[2] = f2bf(v[2]); o[3] = f2bf(v[3]);
    ((us4*)dst)[i] = o;
  }
}

// ---------------- fp32 [b][R][C] -> bf16 [b][C][R] transpose+cast ----------------
__global__ __launch_bounds__(256) void transpose_cast_kernel(
    const float* __restrict__ src, unsigned short* __restrict__ dst, int R, int C) {
  __shared__ float tile[32][33];
  size_t base = (size_t)blockIdx.z * R * C;
  int c0 = blockIdx.x * 32, r0 = blockIdx.y * 32;
  int tx = threadIdx.x, ty = threadIdx.y;  // 32 x 8
#pragma unroll
  for (int j = 0; j < 32; j += 8)
    tile[ty + j][tx] = src[base + (size_t)(r0 + ty + j) * C + c0 + tx];
  __syncthreads();
#pragma unroll
  for (int j = 0; j < 32; j += 8)
    dst[base + (size_t)(c0 + ty + j) * R + r0 + tx] = f2bf(tile[tx][ty + j]);
}

// ---------------- TN bf16 MFMA GEMM, 128x128 tile, BK=32 (m97 structure) ----------------
// C[m,n] = sum_k A[m,k]*BT[n,k] + bias[n]; optional silu; out bf16 or fp32.
template <int SILU, int OUTBF>
__global__ __launch_bounds__(256) void gemm_tn_kernel(
    const unsigned short* __restrict__ A, const unsigned short* __restrict__ BT,
    const float* __restrict__ bias, void* __restrict__ Cptr,
    int M, int N, int K, int ldc) {
  __shared__ unsigned short Als[128 * 32];  // [row][k] linear, 8KB
  __shared__ unsigned short Bls[128 * 32];  // [col][k] linear, 8KB
  const int tid = threadIdx.x;
  const int wave = tid >> 6, lane = tid & 63;
  const int row0 = blockIdx.y * 128, col0 = blockIdx.x * 128;
  const int wm = wave >> 1, wn = wave & 1;  // 2x2 waves of 64x64
  f4 acc[4][4] = {};

  // fragment LDS element offsets: row = (lane&15), kchunk = (lane>>4)*8
  const int aoff = (wm * 64 + (lane & 15)) * 32 + (lane >> 4) * 8;
  const int boff = (wn * 64 + (lane & 15)) * 32 + (lane >> 4) * 8;

  // staging: 512 chunks of 16B per tile, 2 passes of 256 threads
  const int L0 = tid, L1 = tid + 256;
  const size_t aofs0 = (size_t)(row0 + (L0 >> 2)) * K + (L0 & 3) * 8;
  const size_t aofs1 = (size_t)(row0 + (L1 >> 2)) * K + (L1 & 3) * 8;
  const size_t bofs0 = (size_t)(col0 + (L0 >> 2)) * K + (L0 & 3) * 8;
  const size_t bofs1 = (size_t)(col0 + (L1 >> 2)) * K + (L1 & 3) * 8;
  char* abase0 = (char*)Als + wave * 1024;
  char* abase1 = (char*)Als + 4096 + wave * 1024;
  char* bbase0 = (char*)Bls + wave * 1024;
  char* bbase1 = (char*)Bls + 4096 + wave * 1024;

  for (int k0 = 0; k0 < K; k0 += 32) {
    gload16(A + aofs0 + k0, abase0);
    gload16(A + aofs1 + k0, abase1);
    gload16(BT + bofs0 + k0, bbase0);
    gload16(BT + bofs1 + k0, bbase1);
    __syncthreads();
    short8 af[4], bfr[4];
#pragma unroll
    for (int i = 0; i < 4; i++) af[i] = *(const short8*)&Als[aoff + i * 512];
#pragma unroll
    for (int j = 0; j < 4; j++) bfr[j] = *(const short8*)&Bls[boff + j * 512];
#pragma unroll
    for (int i = 0; i < 4; i++)
#pragma unroll
      for (int j = 0; j < 4; j++)
        acc[i][j] = __builtin_amdgcn_mfma_f32_16x16x32_bf16(af[i], bfr[j], acc[i][j], 0, 0, 0);
    __syncthreads();
  }

  // C/D layout: col = lane&15, row = (lane>>4)*4 + reg
  const int crow = row0 + wm * 64 + (lane >> 4) * 4;
  const int ccol = col0 + wn * 64 + (lane & 15);
#pragma unroll
  for (int j = 0; j < 4; j++) {
    const int col = ccol + j * 16;
    const float bv = bias ? bias[col] : 0.0f;
#pragma unroll
    for (int i = 0; i < 4; i++) {
#pragma unroll
      for (int r = 0; r < 4; r++) {
        float v = acc[i][j][r] + bv;
        if (SILU) v = v / (1.0f + __expf(-v));
        const size_t idx = (size_t)(crow + i * 16 + r) * ldc + col;
        if (OUTBF)
          ((unsigned short*)Cptr)[idx] = f2bf(v);
        else
          ((float*)Cptr)[idx] = v;
      }
    }
  }
}

// ---------------- gating: logits = gh @ gW2 + gb2, softmax over 8 experts ----------------
__global__ __launch_bounds__(256) void gate_kernel(
    const unsigned short* __restrict__ gh, const float* __restrict__ gW2,
    const float* __restrict__ gb2, float* __restrict__ wout) {
  __shared__ float sW[NEXP * GHID];  // transposed [e][k], 16KB
  int tid = threadIdx.x;
  for (int i = tid; i < GHID * NEXP; i += 256) {
    int k = i >> 3, e = i & 7;
    sW[e * GHID + k] = gW2[i];
  }
  __syncthreads();
  int wave = tid >> 6, lane = tid & 63;
  int row = blockIdx.x * 4 + wave;
  float acc[NEXP] = {};
#pragma unroll
  for (int i = 0; i < 8; i++) {
    int k = lane + 64 * i;
    float x = bf2f(gh[(size_t)row * GHID + k]);
#pragma unroll
    for (int e = 0; e < NEXP; e++) acc[e] += x * sW[e * GHID + k];
  }
#pragma unroll
  for (int off = 32; off; off >>= 1)
#pragma unroll
    for (int e = 0; e < NEXP; e++) acc[e] += __shfl_xor(acc[e], off);
  float lg[NEXP], mx = -1e30f;
#pragma unroll
  for (int e = 0; e < NEXP; e++) { lg[e] = acc[e] + gb2[e]; mx = fmaxf(mx, lg[e]); }
  float s = 0.f;
#pragma unroll
  for (int e = 0; e < NEXP; e++) { lg[e] = __expf(lg[e] - mx); s += lg[e]; }
  if (lane < NEXP) wout[(size_t)row * NEXP + lane] = lg[lane] / s;
}

// ---------------- per-expert LayerNorm + gated accumulate into out ----------------
__global__ __launch_bounds__(256) void ln_acc_kernel(
    const float* __restrict__ o, const float* __restrict__ wgate, int e,
    const float* __restrict__ ln_g, const float* __restrict__ ln_b,
    float* __restrict__ out, int first) {
  int wave = threadIdx.x >> 6, lane = threadIdx.x & 63;
  int row = blockIdx.x * 4 + wave;
  const float* orow = o + (size_t)row * DDIM;
  float xs[16];
  float s = 0.f, s2 = 0.f;
#pragma unroll
  for (int q = 0; q < 4; q++) {
    f4 t = *(const f4*)&orow[q * 256 + lane * 4];
#pragma unroll
    for (int u = 0; u < 4; u++) {
      xs[q * 4 + u] = t[u];
      s += t[u];
      s2 += t[u] * t[u];
    }
  }
#pragma unroll
  for (int off = 32; off; off >>= 1) {
    s += __shfl_xor(s, off);
    s2 += __shfl_xor(s2, off);
  }
  const float inv = 1.0f / 1024.0f;
  float mu = s * inv;
  float var = s2 * inv - mu * mu;
  float r = rsqrtf(var + 1e-5f);
  float wv = wgate[(size_t)row * NEXP + e];
  size_t rowbase = (size_t)row * DDIM;
#pragma unroll
  for (int q = 0; q < 4; q++) {
    int d = q * 256 + lane * 4;
    f4 g = *(const f4*)&ln_g[(size_t)e * DDIM + d];
    f4 b = *(const f4*)&ln_b[(size_t)e * DDIM + d];
    f4 prev;
    if (first) prev = (f4){0.f, 0.f, 0.f, 0.f};
    else prev = *(const f4*)&out[rowbase + d];
    f4 res;
#pragma unroll
    for (int u = 0; u < 4; u++)
      res[u] = prev[u] + wv * ((xs[q * 4 + u] - mu) * r * g[u] + b[u]);
    *(f4*)&out[rowbase + d] = res;
  }
}

extern "C" void kernel_launch(void* const* d_in, const int* in_sizes, int n_in,
                              void* d_out, int out_size, void* d_ws, size_t ws_size,
                              hipStream_t stream) {
  const float* text  = (const float*)d_in[0];
  const float* image = (const float*)d_in[1];
  const float* Wt    = (const float*)d_in[2];
  const float* bt    = (const float*)d_in[3];
  const float* Wi    = (const float*)d_in[4];
  const float* bi    = (const float*)d_in[5];
  const float* eW1   = (const float*)d_in[6];
  const float* eb1   = (const float*)d_in[7];
  const float* eW2   = (const float*)d_in[8];
  const float* eb2   = (const float*)d_in[9];
  const float* ln_g  = (const float*)d_in[10];
  const float* ln_b  = (const float*)d_in[11];
  const float* gW1   = (const float*)d_in[12];
  const float* gb1   = (const float*)d_in[13];
  const float* gW2   = (const float*)d_in[14];
  const float* gb2   = (const float*)d_in[15];
  float* out = (float*)d_out;

  size_t off = 0;
  auto alloc = [&](size_t bytes) -> void* {
    void* p = (char*)d_ws + off;
    off += (bytes + 255) & ~(size_t)255;
    return p;
  };
  unsigned short* text_bf = (unsigned short*)alloc((size_t)NROWS * TDIM * 2);
  unsigned short* img_bf  = (unsigned short*)alloc((size_t)NROWS * IDIM * 2);
  unsigned short* WtT     = (unsigned short*)alloc((size_t)TDIM * DDIM * 2);
  unsigned short* WiT     = (unsigned short*)alloc((size_t)IDIM * DDIM * 2);
  unsigned short* gW1T    = (unsigned short*)alloc((size_t)2 * DDIM * GHID * 2);
  unsigned short* eW1T    = (unsigned short*)alloc((size_t)NEXP * 2 * DDIM * DDIM * 2);
  unsigned short* eW2T    = (unsigned short*)alloc((size_t)NEXP * DDIM * DDIM * 2);
  unsigned short* c_bf    = (unsigned short*)alloc((size_t)NROWS * 2 * DDIM * 2);
  unsigned short* gh_bf   = (unsigned short*)alloc((size_t)NROWS * GHID * 2);
  float* wgate            = (float*)alloc((size_t)NROWS * NEXP * 4);
  unsigned short* h_bf    = (unsigned short*)alloc((size_t)NROWS * DDIM * 2);
  float* o_f32            = (float*)alloc((size_t)NROWS * DDIM * 4);

  // 1) casts of activations
  cast_bf16_kernel<<<(NROWS * TDIM / 4 + 255) / 256, 256, 0, stream>>>(text, text_bf, NROWS * TDIM / 4);
  cast_bf16_kernel<<<(NROWS * IDIM / 4 + 255) / 256, 256, 0, stream>>>(image, img_bf, NROWS * IDIM / 4);

  // 2) weight transpose+cast: [R][C] -> [C][R]
  transpose_cast_kernel<<<dim3(DDIM / 32, TDIM / 32, 1), dim3(32, 8), 0, stream>>>(Wt, WtT, TDIM, DDIM);
  transpose_cast_kernel<<<dim3(DDIM / 32, IDIM / 32, 1), dim3(32, 8), 0, stream>>>(Wi, WiT, IDIM, DDIM);
  transpose_cast_kernel<<<dim3(GHID / 32, 2 * DDIM / 32, 1), dim3(32, 8), 0, stream>>>(gW1, gW1T, 2 * DDIM, GHID);
  transpose_cast_kernel<<<dim3(DDIM / 32, 2 * DDIM / 32, NEXP), dim3(32, 8), 0, stream>>>(eW1, eW1T, 2 * DDIM, DDIM);
  transpose_cast_kernel<<<dim3(DDIM / 32, DDIM / 32, NEXP), dim3(32, 8), 0, stream>>>(eW2, eW2T, DDIM, DDIM);

  // 3) projections into c = [ta | ia]  (bf16, ldc=2048)
  gemm_tn_kernel<0, 1><<<dim3(DDIM / 128, NROWS / 128), 256, 0, stream>>>(
      text_bf, WtT, bt, c_bf, NROWS, DDIM, TDIM, 2 * DDIM);
  gemm_tn_kernel<0, 1><<<dim3(DDIM / 128, NROWS / 128), 256, 0, stream>>>(
      img_bf, WiT, bi, c_bf + DDIM, NROWS, DDIM, IDIM, 2 * DDIM);

  // 4) gating hidden: gh = silu(c @ gW1 + gb1), bf16
  gemm_tn_kernel<1, 1><<<dim3(GHID / 128, NROWS / 128), 256, 0, stream>>>(
      c_bf, gW1T, gb1, gh_bf, NROWS, GHID, 2 * DDIM, GHID);

  // 5) gate weights (softmax)
  gate_kernel<<<NROWS / 4, 256, 0, stream>>>(gh_bf, gW2, gb2, wgate);

  // 6) experts
  for (int e = 0; e < NEXP; e++) {
    gemm_tn_kernel<1, 1><<<dim3(DDIM / 128, NROWS / 128), 256, 0, stream>>>(
        c_bf, eW1T + (size_t)e * 2 * DDIM * DDIM, eb1 + (size_t)e * DDIM,
        h_bf, NROWS, DDIM, 2 * DDIM, DDIM);
    gemm_tn_kernel<0, 0><<<dim3(DDIM / 128, NROWS / 128), 256, 0, stream>>>(
        h_bf, eW2T + (size_t)e * DDIM * DDIM, eb2 + (size_t)e * DDIM,
        o_f32, NROWS, DDIM, DDIM, DDIM);
    ln_acc_kernel<<<NROWS / 4, 256, 0, stream>>>(o_f32, wgate, e, ln_g, ln_b, out, e == 0);
  }
}

// Round 2
// 955.878 us; speedup vs baseline: 1.1193x; 1.1193x over previous
//
#include <hip/hip_runtime.h>

#define NROWS 8192
#define TDIM 768
#define IDIM 1024
#define DDIM 1024
#define NEXP 8
#define GHID 512

typedef __attribute__((ext_vector_type(8))) short short8;
typedef __attribute__((ext_vector_type(4))) float f4;
typedef __attribute__((ext_vector_type(4))) unsigned short us4;

__device__ __forceinline__ unsigned short f2bf(float f) {
  union { float f; unsigned u; } v; v.f = f;
  unsigned r = v.u + 0x7FFF + ((v.u >> 16) & 1);
  return (unsigned short)(r >> 16);
}
__device__ __forceinline__ float bf2f(unsigned short u) {
  union { unsigned u; float f; } v; v.u = ((unsigned)u) << 16;
  return v.f;
}

__device__ __forceinline__ void gload16(const void* g, void* l) {
  __builtin_amdgcn_global_load_lds(
      (const __attribute__((address_space(1))) void*)g,
      (__attribute__((address_space(3))) void*)l, 16, 0, 0);
}

// ---------------- fp32 -> bf16 elementwise cast (vectorized) ----------------
__global__ __launch_bounds__(256) void cast_bf16_kernel(
    const float* __restrict__ src, unsigned short* __restrict__ dst, int n4) {
  int i = blockIdx.x * 256 + threadIdx.x;
  if (i < n4) {
    f4 v = ((const f4*)src)[i];
    us4 o;
    o[0] = f2bf(v[0]); o[1] = f2bf(v[1]); o[2] = f2bf(v[2]); o[3] = f2bf(v[3]);
    ((us4*)dst)[i] = o;
  }
}

// ---------------- fp32 [b][R][C] -> bf16 [b][C][R] transpose+cast ----------------
__global__ __launch_bounds__(256) void transpose_cast_kernel(
    const float* __restrict__ src, unsigned short* __restrict__ dst, int R, int C) {
  __shared__ float tile[32][33];
  size_t base = (size_t)blockIdx.z * R * C;
  int c0 = blockIdx.x * 32, r0 = blockIdx.y * 32;
  int tx = threadIdx.x, ty = threadIdx.y;  // 32 x 8
#pragma unroll
  for (int j = 0; j < 32; j += 8)
    tile[ty + j][tx] = src[base + (size_t)(r0 + ty + j) * C + c0 + tx];
  __syncthreads();
#pragma unroll
  for (int j = 0; j < 32; j += 8)
    dst[base + (size_t)(c0 + ty + j) * R + r0 + tx] = f2bf(tile[tx][ty + j]);
}

// ---------------- TN bf16 MFMA GEMM, 128x128 tile, BK=32 (m97 structure) ----------------
// Grid covers (N/128, M/128, batch). C[m,n] = sum_k A[m,k]*BT[n,k] + bias[n].
// Optional silu; out bf16 or fp32. Batch strides in elements.
template <int SILU, int OUTBF>
__global__ __launch_bounds__(256) void gemm_tn_kernel(
    const unsigned short* __restrict__ A, const unsigned short* __restrict__ BT,
    const float* __restrict__ bias, void* __restrict__ Cptr,
    int K, int lda, int ldb, int ldc,
    size_t sA, size_t sB, size_t sBias, size_t sC) {
  __shared__ unsigned short Als[128 * 32];  // [row][k] linear, 8KB
  __shared__ unsigned short Bls[128 * 32];  // [col][k] linear, 8KB

  const unsigned short* Ab = A + (size_t)blockIdx.z * sA;
  const unsigned short* Bb = BT + (size_t)blockIdx.z * sB;
  const float* biasb = bias + (size_t)blockIdx.z * sBias;

  // XCD-aware bijective block swizzle (T1, m204 general formula)
  const int gx = gridDim.x;
  const int nwg = gx * gridDim.y;
  const int orig = blockIdx.y * gx + blockIdx.x;
  const int q = nwg >> 3, r = nwg & 7;
  const int xcd = orig & 7, idx = orig >> 3;
  const int wgid = (xcd < r ? xcd * (q + 1) : r * (q + 1) + (xcd - r) * q) + idx;
  const int bx = wgid % gx, by = wgid / gx;

  const int tid = threadIdx.x;
  const int wave = tid >> 6, lane = tid & 63;
  const int row0 = by * 128, col0 = bx * 128;
  const int wm = wave >> 1, wn = wave & 1;  // 2x2 waves of 64x64
  f4 acc[4][4] = {};

  // fragment LDS element offsets: row = (lane&15), kchunk = (lane>>4)*8
  const int aoff = (wm * 64 + (lane & 15)) * 32 + (lane >> 4) * 8;
  const int boff = (wn * 64 + (lane & 15)) * 32 + (lane >> 4) * 8;

  // staging: 512 chunks of 16B per tile, 2 passes of 256 threads
  const int L0 = tid, L1 = tid + 256;
  const size_t aofs0 = (size_t)(row0 + (L0 >> 2)) * lda + (L0 & 3) * 8;
  const size_t aofs1 = (size_t)(row0 + (L1 >> 2)) * lda + (L1 & 3) * 8;
  const size_t bofs0 = (size_t)(col0 + (L0 >> 2)) * ldb + (L0 & 3) * 8;
  const size_t bofs1 = (size_t)(col0 + (L1 >> 2)) * ldb + (L1 & 3) * 8;
  char* abase0 = (char*)Als + wave * 1024;
  char* abase1 = (char*)Als + 4096 + wave * 1024;
  char* bbase0 = (char*)Bls + wave * 1024;
  char* bbase1 = (char*)Bls + 4096 + wave * 1024;

  for (int k0 = 0; k0 < K; k0 += 32) {
    gload16(Ab + aofs0 + k0, abase0);
    gload16(Ab + aofs1 + k0, abase1);
    gload16(Bb + bofs0 + k0, bbase0);
    gload16(Bb + bofs1 + k0, bbase1);
    __syncthreads();
    short8 af[4], bfr[4];
#pragma unroll
    for (int i = 0; i < 4; i++) af[i] = *(const short8*)&Als[aoff + i * 512];
#pragma unroll
    for (int j = 0; j < 4; j++) bfr[j] = *(const short8*)&Bls[boff + j * 512];
#pragma unroll
    for (int i = 0; i < 4; i++)
#pragma unroll
      for (int j = 0; j < 4; j++)
        acc[i][j] = __builtin_amdgcn_mfma_f32_16x16x32_bf16(af[i], bfr[j], acc[i][j], 0, 0, 0);
    __syncthreads();
  }

  // C/D layout: col = lane&15, row = (lane>>4)*4 + reg
  const int crow = row0 + wm * 64 + (lane >> 4) * 4;
  const int ccol = col0 + wn * 64 + (lane & 15);
  char* Cb = (char*)Cptr + (size_t)blockIdx.z * sC * (OUTBF ? 2 : 4);
#pragma unroll
  for (int j = 0; j < 4; j++) {
    const int col = ccol + j * 16;
    const float bv = biasb[col];
#pragma unroll
    for (int i = 0; i < 4; i++) {
#pragma unroll
      for (int r2 = 0; r2 < 4; r2++) {
        float v = acc[i][j][r2] + bv;
        if (SILU) v = v / (1.0f + __expf(-v));
        const size_t cidx = (size_t)(crow + i * 16 + r2) * ldc + col;
        if (OUTBF)
          ((unsigned short*)Cb)[cidx] = f2bf(v);
        else
          ((float*)Cb)[cidx] = v;
      }
    }
  }
}

// ---------------- gating: logits = gh @ gW2 + gb2, softmax over 8 experts ----------------
__global__ __launch_bounds__(256) void gate_kernel(
    const unsigned short* __restrict__ gh, const float* __restrict__ gW2,
    const float* __restrict__ gb2, float* __restrict__ wout) {
  __shared__ float sW[NEXP * GHID];  // transposed [e][k], 16KB
  int tid = threadIdx.x;
  for (int i = tid; i < GHID * NEXP; i += 256) {
    int k = i >> 3, e = i & 7;
    sW[e * GHID + k] = gW2[i];
  }
  __syncthreads();
  int wave = tid >> 6, lane = tid & 63;
  int row = blockIdx.x * 4 + wave;
  float acc[NEXP] = {};
#pragma unroll
  for (int i = 0; i < 8; i++) {
    int k = lane + 64 * i;
    float x = bf2f(gh[(size_t)row * GHID + k]);
#pragma unroll
    for (int e = 0; e < NEXP; e++) acc[e] += x * sW[e * GHID + k];
  }
#pragma unroll
  for (int off = 32; off; off >>= 1)
#pragma unroll
    for (int e = 0; e < NEXP; e++) acc[e] += __shfl_xor(acc[e], off);
  float lg[NEXP], mx = -1e30f;
#pragma unroll
  for (int e = 0; e < NEXP; e++) { lg[e] = acc[e] + gb2[e]; mx = fmaxf(mx, lg[e]); }
  float s = 0.f;
#pragma unroll
  for (int e = 0; e < NEXP; e++) { lg[e] = __expf(lg[e] - mx); s += lg[e]; }
  if (lane < NEXP) wout[(size_t)row * NEXP + lane] = lg[lane] / s;
}

// ---------------- LayerNorm + gated accumulate over a group of g experts ----------------
// o: [NROWS][g*1024] fp32 (expert j of group at cols j*1024..). One wave per row.
__global__ __launch_bounds__(256) void ln_acc_kernel(
    const float* __restrict__ o, const float* __restrict__ wgate, int go, int g,
    const float* __restrict__ ln_g, const float* __restrict__ ln_b,
    float* __restrict__ out, int first) {
  int wave = threadIdx.x >> 6, lane = threadIdx.x & 63;
  int row = blockIdx.x * 4 + wave;
  const int ldo = g * DDIM;
  float res[16];
  size_t rowbase = (size_t)row * DDIM;
  if (first) {
#pragma unroll
    for (int u = 0; u < 16; u++) res[u] = 0.f;
  } else {
#pragma unroll
    for (int qq = 0; qq < 4; qq++) {
      f4 t = *(const f4*)&out[rowbase + qq * 256 + lane * 4];
#pragma unroll
      for (int u = 0; u < 4; u++) res[qq * 4 + u] = t[u];
    }
  }
  for (int j = 0; j < g; j++) {
    const int e = go + j;
    const float* orow = o + (size_t)row * ldo + (size_t)j * DDIM;
    float xs[16];
    float s = 0.f, s2 = 0.f;
#pragma unroll
    for (int qq = 0; qq < 4; qq++) {
      f4 t = *(const f4*)&orow[qq * 256 + lane * 4];
#pragma unroll
      for (int u = 0; u < 4; u++) {
        xs[qq * 4 + u] = t[u];
        s += t[u];
        s2 += t[u] * t[u];
      }
    }
#pragma unroll
    for (int off = 32; off; off >>= 1) {
      s += __shfl_xor(s, off);
      s2 += __shfl_xor(s2, off);
    }
    const float inv = 1.0f / 1024.0f;
    float mu = s * inv;
    float var = s2 * inv - mu * mu;
    float rr = rsqrtf(var + 1e-5f);
    float wv = wgate[(size_t)row * NEXP + e];
#pragma unroll
    for (int qq = 0; qq < 4; qq++) {
      int d = qq * 256 + lane * 4;
      f4 gg = *(const f4*)&ln_g[(size_t)e * DDIM + d];
      f4 bb = *(const f4*)&ln_b[(size_t)e * DDIM + d];
#pragma unroll
      for (int u = 0; u < 4; u++)
        res[qq * 4 + u] += wv * ((xs[qq * 4 + u] - mu) * rr * gg[u] + bb[u]);
    }
  }
#pragma unroll
  for (int qq = 0; qq < 4; qq++) {
    f4 t;
#pragma unroll
    for (int u = 0; u < 4; u++) t[u] = res[qq * 4 + u];
    *(f4*)&out[rowbase + qq * 256 + lane * 4] = t;
  }
}

extern "C" void kernel_launch(void* const* d_in, const int* in_sizes, int n_in,
                              void* d_out, int out_size, void* d_ws, size_t ws_size,
                              hipStream_t stream) {
  const float* text  = (const float*)d_in[0];
  const float* image = (const float*)d_in[1];
  const float* Wt    = (const float*)d_in[2];
  const float* bt    = (const float*)d_in[3];
  const float* Wi    = (const float*)d_in[4];
  const float* bi    = (const float*)d_in[5];
  const float* eW1   = (const float*)d_in[6];
  const float* eb1   = (const float*)d_in[7];
  const float* eW2   = (const float*)d_in[8];
  const float* eb2   = (const float*)d_in[9];
  const float* ln_g  = (const float*)d_in[10];
  const float* ln_b  = (const float*)d_in[11];
  const float* gW1   = (const float*)d_in[12];
  const float* gb1   = (const float*)d_in[13];
  const float* gW2   = (const float*)d_in[14];
  const float* gb2   = (const float*)d_in[15];
  float* out = (float*)d_out;

  size_t off = 0;
  auto alloc = [&](size_t bytes) -> void* {
    void* p = (char*)d_ws + off;
    off += (bytes + 255) & ~(size_t)255;
    return p;
  };
  unsigned short* text_bf = (unsigned short*)alloc((size_t)NROWS * TDIM * 2);
  unsigned short* img_bf  = (unsigned short*)alloc((size_t)NROWS * IDIM * 2);
  unsigned short* WtT     = (unsigned short*)alloc((size_t)TDIM * DDIM * 2);
  unsigned short* WiT     = (unsigned short*)alloc((size_t)IDIM * DDIM * 2);
  unsigned short* gW1T    = (unsigned short*)alloc((size_t)2 * DDIM * GHID * 2);
  unsigned short* eW1T    = (unsigned short*)alloc((size_t)NEXP * 2 * DDIM * DDIM * 2);
  unsigned short* eW2T    = (unsigned short*)alloc((size_t)NEXP * DDIM * DDIM * 2);
  unsigned short* c_bf    = (unsigned short*)alloc((size_t)NROWS * 2 * DDIM * 2);
  unsigned short* gh_bf   = (unsigned short*)alloc((size_t)NROWS * GHID * 2);
  float* wgate            = (float*)alloc((size_t)NROWS * NEXP * 4);

  // dynamic expert-group size: g experts processed per {W1, W2, LN} sweep.
  // per-g cost: h (bf16, 16.78 MB) + o (f32, 33.55 MB) per expert
  size_t fixed = off;
  int g = NEXP;
  while (g > 1 && fixed + (size_t)g * ((size_t)NROWS * DDIM * 2 + (size_t)NROWS * DDIM * 4) > ws_size)
    g >>= 1;
  unsigned short* h_g = (unsigned short*)alloc((size_t)NROWS * DDIM * g * 2);
  float* o_g          = (float*)alloc((size_t)NROWS * DDIM * g * 4);

  // 1) casts of activations
  cast_bf16_kernel<<<(NROWS * TDIM / 4 + 255) / 256, 256, 0, stream>>>(text, text_bf, NROWS * TDIM / 4);
  cast_bf16_kernel<<<(NROWS * IDIM / 4 + 255) / 256, 256, 0, stream>>>(image, img_bf, NROWS * IDIM / 4);

  // 2) weight transpose+cast: [R][C] -> [C][R]
  transpose_cast_kernel<<<dim3(DDIM / 32, TDIM / 32, 1), dim3(32, 8), 0, stream>>>(Wt, WtT, TDIM, DDIM);
  transpose_cast_kernel<<<dim3(DDIM / 32, IDIM / 32, 1), dim3(32, 8), 0, stream>>>(Wi, WiT, IDIM, DDIM);
  transpose_cast_kernel<<<dim3(GHID / 32, 2 * DDIM / 32, 1), dim3(32, 8), 0, stream>>>(gW1, gW1T, 2 * DDIM, GHID);
  transpose_cast_kernel<<<dim3(DDIM / 32, 2 * DDIM / 32, NEXP), dim3(32, 8), 0, stream>>>(eW1, eW1T, 2 * DDIM, DDIM);
  transpose_cast_kernel<<<dim3(DDIM / 32, DDIM / 32, NEXP), dim3(32, 8), 0, stream>>>(eW2, eW2T, DDIM, DDIM);

  // 3) projections into c = [ta | ia]  (bf16, ldc=2048)
  gemm_tn_kernel<0, 1><<<dim3(DDIM / 128, NROWS / 128), 256, 0, stream>>>(
      text_bf, WtT, bt, c_bf, TDIM, TDIM, TDIM, 2 * DDIM, 0, 0, 0, 0);
  gemm_tn_kernel<0, 1><<<dim3(DDIM / 128, NROWS / 128), 256, 0, stream>>>(
      img_bf, WiT, bi, c_bf + DDIM, IDIM, IDIM, IDIM, 2 * DDIM, 0, 0, 0, 0);

  // 4) gating hidden: gh = silu(c @ gW1 + gb1), bf16
  gemm_tn_kernel<1, 1><<<dim3(GHID / 128, NROWS / 128), 256, 0, stream>>>(
      c_bf, gW1T, gb1, gh_bf, 2 * DDIM, 2 * DDIM, 2 * DDIM, GHID, 0, 0, 0, 0);

  // 5) gate weights (softmax)
  gate_kernel<<<NROWS / 4, 256, 0, stream>>>(gh_bf, gW2, gb2, wgate);

  // 6) experts, in groups of g
  for (int go = 0; go < NEXP; go += g) {
    // W1 for the whole group as ONE GEMM: N = g*1024 columns (eW1T rows contiguous)
    gemm_tn_kernel<1, 1><<<dim3(g * DDIM / 128, NROWS / 128), 256, 0, stream>>>(
        c_bf, eW1T + (size_t)go * 2 * DDIM * DDIM, eb1 + (size_t)go * DDIM,
        h_g, 2 * DDIM, 2 * DDIM, 2 * DDIM, g * DDIM, 0, 0, 0, 0);
    // W2 batched over experts in the group via blockIdx.z
    gemm_tn_kernel<0, 0><<<dim3(DDIM / 128, NROWS / 128, g), 256, 0, stream>>>(
        h_g, eW2T + (size_t)go * DDIM * DDIM, eb2 + (size_t)go * DDIM,
        o_g, DDIM, g * DDIM, DDIM, g * DDIM,
        (size_t)DDIM, (size_t)DDIM * DDIM, (size_t)DDIM, (size_t)DDIM);
    // LN + gated accumulate for the group
    ln_acc_kernel<<<NROWS / 4, 256, 0, stream>>>(o_g, wgate, go, g, ln_g, ln_b, out, go == 0);
  }
}